// Round 9
// baseline (318.934 us; speedup 1.0000x reference)
//
#include <hip/hip_runtime.h>
#include <hip/hip_bf16.h>
#include <cstdint>

#define B_SZ 16
#define C_IN 512
#define C8   64
#define NSP  4096   // H*W
#define QR   192    // q,k,v stacked rows

typedef __attribute__((ext_vector_type(8))) short s8v;   // 8 bf16 (4 VGPRs)
typedef __attribute__((ext_vector_type(4))) float f4v;   // MFMA acc

// split fp32 -> truncated bf16 hi + bf16(residual). |x - hi - lo| <= ~2^-16 |x|
__device__ __forceinline__ void split_bf16(float x, unsigned short& h, unsigned short& l) {
    unsigned int u = __float_as_uint(x);
    h = (unsigned short)(u >> 16);
    float r = x - __uint_as_float(u & 0xffff0000u);
    l = (unsigned short)(__float_as_uint(r) >> 16);
}

__device__ __forceinline__ void split8(const float* v, s8v& h, s8v& l) {
#pragma unroll
    for (int j = 0; j < 8; ++j) {
        unsigned short hh, ll;
        split_bf16(v[j], hh, ll);
        h[j] = (short)hh; l[j] = (short)ll;
    }
}

// swizzled address into the fp32 [128][128] epilogue LDS (floats).
__device__ __forceinline__ int eqaddr(int row, int n) {
    return row * 128 + ((((n >> 2) ^ ((row & 7) << 2)) << 2) | (n & 3));
}

// ---------------------------------------------------------------------------
// K1: fused QKV projection + partial energy. W split in-kernel (convW folded:
// fp32 W bytes == whi+wlo bytes, identical split math -> bit-identical).
// grid (32, B), 512 thr = 8 waves (4M x 2N). Block tile 192x128, BK=32.
// ---------------------------------------------------------------------------
__global__ __launch_bounds__(512, 4) void k_qkv_en(
    const float* __restrict__ x,
    const float* __restrict__ Wq, const float* __restrict__ Wk,
    const float* __restrict__ Wv,
    const float* __restrict__ bq, const float* __restrict__ bk,
    const float* __restrict__ bv,
    float* __restrict__ v, float* __restrict__ part)
{
    __shared__ __align__(16) unsigned char smem[65536];
    unsigned short* as_h = (unsigned short*)smem;          // [QR*32]
    unsigned short* as_l = as_h + QR * 32;
    unsigned short* xs_h = as_l + QR * 32;                 // [128*32]
    unsigned short* xs_l = xs_h + 128 * 32;
    float* eq = (float*)smem;                              // [128*128] (epilogue)

    const int b  = blockIdx.y;
    const int s  = blockIdx.x;
    const int n0 = s * 128;
    const int t  = threadIdx.x;
    const int w  = t >> 6, l = t & 63;
    const int wm = w >> 1, wn = w & 1;
    const int lm = l & 15, lq = l >> 4;
    const int slot = ((lq ^ (l & 3)) << 3);

    const int nB = t & 127, kgB = t >> 7;
    const int slotB = ((kgB ^ (nB & 3)) << 3);

    // W staging: item0 row m0 = t>>2 (0..127), item1 row m0+128 (t<256 only)
    const int m0 = t >> 2, kg0 = t & 3;
    const float* wr0 = ((m0 < 64) ? (Wq + (size_t)m0 * C_IN)
                                  : (Wk + (size_t)(m0 - 64) * C_IN)) + kg0 * 8;
    const float* wr1 = Wv + (size_t)m0 * C_IN + kg0 * 8;   // row m0+128-128
    const int dst0 = m0 * 32 + ((kg0 ^ (m0 & 3)) << 3);    // item1: +4096

    f4v acc[3][4];
#pragma unroll
    for (int i = 0; i < 3; ++i)
#pragma unroll
        for (int j = 0; j < 4; ++j) acc[i][j] = (f4v)0.f;

    const float* xcol = x + (size_t)b * C_IN * NSP + n0 + nB;
    float xr[8];
    auto loadB = [&](int K0) {
        const float* s_ = xcol + (size_t)(K0 + kgB * 8) * NSP;
#pragma unroll
        for (int j = 0; j < 8; ++j) xr[j] = s_[(size_t)j * NSP];
    };
    loadB(0);

    for (int it = 0; it < 16; ++it) {
        const int k0 = it * 32;
        __syncthreads();
        // split current x chunk (regs) BEFORE prefetch clobbers xr
        s8v hv, lv;
        {
            unsigned short h, lo_;
#pragma unroll
            for (int j = 0; j < 8; ++j) {
                split_bf16(xr[j], h, lo_);
                hv[j] = (short)h; lv[j] = (short)lo_;
            }
        }
        if (it < 15) loadB(k0 + 32);         // next x: latency spans compute
        // W fp32 loads -> regs first (latency hides under x LDS writes)
        float wv0[8], wv1[8];
        *(float4*)&wv0[0] = *(const float4*)(wr0 + k0);
        *(float4*)&wv0[4] = *(const float4*)(wr0 + k0 + 4);
        if (t < 256) {
            *(float4*)&wv1[0] = *(const float4*)(wr1 + k0);
            *(float4*)&wv1[4] = *(const float4*)(wr1 + k0 + 4);
        }
        *(s8v*)&xs_h[nB * 32 + slotB] = hv;
        *(s8v*)&xs_l[nB * 32 + slotB] = lv;
        {
            s8v wh, wl;
            split8(wv0, wh, wl);
            *(s8v*)&as_h[dst0] = wh;
            *(s8v*)&as_l[dst0] = wl;
            if (t < 256) {
                split8(wv1, wh, wl);
                *(s8v*)&as_h[dst0 + 4096] = wh;
                *(s8v*)&as_l[dst0 + 4096] = wl;
            }
        }
        __syncthreads();
        s8v ah[3], al[3], bh[4], bl[4];
#pragma unroll
        for (int fm = 0; fm < 3; ++fm) {
            const int m = wm * 48 + fm * 16 + lm;
            ah[fm] = *(const s8v*)&as_h[m * 32 + slot];
            al[fm] = *(const s8v*)&as_l[m * 32 + slot];
        }
#pragma unroll
        for (int fn = 0; fn < 4; ++fn) {
            const int n = wn * 64 + fn * 16 + lm;
            bh[fn] = *(const s8v*)&xs_h[n * 32 + slot];
            bl[fn] = *(const s8v*)&xs_l[n * 32 + slot];
        }
#pragma unroll
        for (int fm = 0; fm < 3; ++fm)
#pragma unroll
            for (int fn = 0; fn < 4; ++fn) {
                acc[fm][fn] = __builtin_amdgcn_mfma_f32_16x16x32_bf16(
                    ah[fm], bh[fn], acc[fm][fn], 0, 0, 0);
                acc[fm][fn] = __builtin_amdgcn_mfma_f32_16x16x32_bf16(
                    ah[fm], bl[fn], acc[fm][fn], 0, 0, 0);
                acc[fm][fn] = __builtin_amdgcn_mfma_f32_16x16x32_bf16(
                    al[fm], bh[fn], acc[fm][fn], 0, 0, 0);
            }
    }

    // ================= epilogue =================
    __syncthreads();   // all frag reads of staging LDS done; repurpose as eq
#pragma unroll
    for (int fm = 0; fm < 3; ++fm) {
        const int row0f = wm * 48 + fm * 16;   // 16-row segment, class-uniform
        const int rbase = row0f + lq * 4;
        if (row0f >= 128) {
#pragma unroll
            for (int fn = 0; fn < 4; ++fn) {
                const int n = wn * 64 + fn * 16 + lm;
                float* dst = v + ((size_t)b * 64 + (rbase - 128)) * NSP + n0 + n;
#pragma unroll
                for (int r = 0; r < 4; ++r)
                    dst[(size_t)r * NSP] = acc[fm][fn][r] + bv[rbase - 128 + r];
            }
        } else {
            const float* barr = (row0f < 64) ? bq : bk;
            const int boff = rbase & 63;
#pragma unroll
            for (int fn = 0; fn < 4; ++fn) {
                const int n = wn * 64 + fn * 16 + lm;
#pragma unroll
                for (int r = 0; r < 4; ++r)
                    eq[eqaddr(rbase + r, n)] = acc[fm][fn][r] + barr[boff + r];
            }
        }
    }
    __syncthreads();

    // QK^T: wave w -> fc = w>>1, fd = (w&1)*2+{0,1}
    const int fc = w >> 1, fd0 = (w & 1) * 2;
    f4v e0 = (f4v)0.f, e1 = (f4v)0.f;
#pragma unroll
    for (int ks = 0; ks < 4; ++ks) {
        const int nf = ks * 32 + lq * 8;
        float qa[8];
        {
            const int a0 = eqaddr(fc * 16 + lm, nf);
            *(float4*)&qa[0] = *(const float4*)&eq[a0];
            *(float4*)&qa[4] = *(const float4*)&eq[a0 + 4];
        }
        s8v qh, ql_;
        split8(qa, qh, ql_);
        float ka[8];
        {
            const int a0 = eqaddr(64 + fd0 * 16 + lm, nf);
            *(float4*)&ka[0] = *(const float4*)&eq[a0];
            *(float4*)&ka[4] = *(const float4*)&eq[a0 + 4];
        }
        s8v kh, kl_;
        split8(ka, kh, kl_);
        e0 = __builtin_amdgcn_mfma_f32_16x16x32_bf16(qh, kh,  e0, 0, 0, 0);
        e0 = __builtin_amdgcn_mfma_f32_16x16x32_bf16(qh, kl_, e0, 0, 0, 0);
        e0 = __builtin_amdgcn_mfma_f32_16x16x32_bf16(ql_, kh, e0, 0, 0, 0);
        {
            const int a0 = eqaddr(64 + (fd0 + 1) * 16 + lm, nf);
            *(float4*)&ka[0] = *(const float4*)&eq[a0];
            *(float4*)&ka[4] = *(const float4*)&eq[a0 + 4];
        }
        split8(ka, kh, kl_);
        e1 = __builtin_amdgcn_mfma_f32_16x16x32_bf16(qh, kh,  e1, 0, 0, 0);
        e1 = __builtin_amdgcn_mfma_f32_16x16x32_bf16(qh, kl_, e1, 0, 0, 0);
        e1 = __builtin_amdgcn_mfma_f32_16x16x32_bf16(ql_, kh, e1, 0, 0, 0);
    }
    float* pb = part + ((size_t)b * 32 + s) * 4096;
#pragma unroll
    for (int r = 0; r < 4; ++r) {
        const int c = fc * 16 + lq * 4 + r;
        pb[c * 64 + fd0 * 16 + lm]        = e0[r];
        pb[c * 64 + (fd0 + 1) * 16 + lm]  = e1[r];
    }
}

// ---------------------------------------------------------------------------
// K2: fused {reduce partials -> softmax -> M = Wo @ attn -> pre-split store}.
// grid (8, B), 256 thr. Each block redundantly reduces part for its b
// (L2/L3-hot) + softmaxes in-place in LDS, then computes its 64 o-rows of M.
// ---------------------------------------------------------------------------
__global__ __launch_bounds__(256) void k_sm_wo(
    const float* __restrict__ part, const float* __restrict__ Wo,
    unsigned short* __restrict__ mhi, unsigned short* __restrict__ mlo)
{
    __shared__ float es[64][65];     // energy -> attn (in-place)
    __shared__ float wosT[64][68];   // [c][o_local]
    const int b  = blockIdx.y;
    const int o0 = blockIdx.x * 64;
    const int t  = threadIdx.x;
    const int td = t & 15, to = t >> 4;

    // stage Wo^T for this block's o-rows
#pragma unroll
    for (int i = 0; i < 4; ++i) {
        int idx = t + 256 * i;
        int r = idx >> 4, q4 = idx & 15;
        float4 wv = *reinterpret_cast<const float4*>(
            Wo + (size_t)(o0 + r) * 64 + q4 * 4);
        wosT[q4 * 4 + 0][r] = wv.x; wosT[q4 * 4 + 1][r] = wv.y;
        wosT[q4 * 4 + 2][r] = wv.z; wosT[q4 * 4 + 3][r] = wv.w;
    }

    // reduce 32 partial chunks -> es
    const float* p = part + (size_t)b * 32 * 4096;
#pragma unroll
    for (int i = 0; i < 16; ++i) {
        int idx = t + 256 * i;   // 0..4095
        float sum = 0.f;
#pragma unroll 8
        for (int s = 0; s < 32; ++s) sum += p[(size_t)s * 4096 + idx];
        es[idx >> 6][idx & 63] = sum;
    }
    __syncthreads();

    // wave-parallel softmax, in place: wave g handles rows g, g+4, ...
    {
        const int g = t >> 6, d = t & 63;
#pragma unroll
        for (int j = 0; j < 16; ++j) {
            const int r = g + 4 * j;
            float vv = es[r][d];
            float m = vv;
#pragma unroll
            for (int off = 32; off; off >>= 1) m = fmaxf(m, __shfl_xor(m, off));
            float e = __expf(vv - m);
            float sum = e;
#pragma unroll
            for (int off = 32; off; off >>= 1) sum += __shfl_xor(sum, off);
            es[r][d] = e / sum;
        }
    }
    __syncthreads();

    // M tile: 64 o-rows x 64 d, K = 64 (fp32 VALU, tiny)
    float acc[4][4];
#pragma unroll
    for (int i = 0; i < 4; ++i)
#pragma unroll
        for (int j = 0; j < 4; ++j) acc[i][j] = 0.f;
#pragma unroll 8
    for (int kk = 0; kk < 64; ++kk) {
        float4 wv = *reinterpret_cast<const float4*>(&wosT[kk][to * 4]);
        float4 av = *reinterpret_cast<const float4*>(&es[kk][td * 4]);
        const float wr[4] = {wv.x, wv.y, wv.z, wv.w};
        const float ar[4] = {av.x, av.y, av.z, av.w};
#pragma unroll
        for (int i = 0; i < 4; ++i)
#pragma unroll
            for (int j = 0; j < 4; ++j)
                acc[i][j] = fmaf(wr[i], ar[j], acc[i][j]);
    }
#pragma unroll
    for (int i = 0; i < 4; ++i) {
        unsigned short h[4], lo4[4];
#pragma unroll
        for (int j = 0; j < 4; ++j) split_bf16(acc[i][j], h[j], lo4[j]);
        const size_t base = ((size_t)b * 512 + o0 + to * 4 + i) * 64 + td * 4;
        uint2 hp, lp;
        hp.x = (unsigned)h[0]   | ((unsigned)h[1]   << 16);
        hp.y = (unsigned)h[2]   | ((unsigned)h[3]   << 16);
        lp.x = (unsigned)lo4[0] | ((unsigned)lo4[1] << 16);
        lp.y = (unsigned)lo4[2] | ((unsigned)lo4[3] << 16);
        *reinterpret_cast<uint2*>(&mhi[base]) = hp;
        *reinterpret_cast<uint2*>(&mlo[base]) = lp;
    }
}

// ---------------------------------------------------------------------------
// K3: out = M @ v + bo. grid (64, B), 512 thr = 8 waves; v read once.
// ---------------------------------------------------------------------------
__global__ __launch_bounds__(512, 2) void k_out2(
    const float* __restrict__ v,
    const unsigned short* __restrict__ mhi, const unsigned short* __restrict__ mlo,
    const float* __restrict__ bo, float* __restrict__ out)
{
    __shared__ unsigned short vsT_h[64 * 64];   // [n][d], swizzled
    __shared__ unsigned short vsT_l[64 * 64];
    const int b  = blockIdx.y;
    const int n0 = blockIdx.x * 64;
    const int t  = threadIdx.x;
    const int w  = t >> 6, l = t & 63;
    const int lm = l & 15, lq = l >> 4;

#pragma unroll
    for (int i = 0; i < 8; ++i) {
        const int d = w * 8 + i;
        const float xv = v[((size_t)b * 64 + d) * NSP + n0 + l];
        unsigned short h, lo_;
        split_bf16(xv, h, lo_);
        const int addr = l * 64 + ((((d >> 3) ^ (l & 7))) << 3) + (d & 7);
        vsT_h[addr] = h;
        vsT_l[addr] = lo_;
    }
    __syncthreads();

    f4v acc[4][4];
#pragma unroll
    for (int i = 0; i < 4; ++i)
#pragma unroll
        for (int j = 0; j < 4; ++j) acc[i][j] = (f4v)0.f;

    const int obase = w * 64;
#pragma unroll
    for (int ks = 0; ks < 2; ++ks) {
        s8v bh[4], bl[4];
#pragma unroll
        for (int fn = 0; fn < 4; ++fn) {
            const int n = fn * 16 + lm;
            const int addr = n * 64 + ((((ks * 4 + lq) ^ (n & 7))) << 3);
            bh[fn] = *(const s8v*)&vsT_h[addr];
            bl[fn] = *(const s8v*)&vsT_l[addr];
        }
#pragma unroll
        for (int fo = 0; fo < 4; ++fo) {
            const int o = obase + fo * 16 + lm;
            const size_t moff = ((size_t)b * 512 + o) * 64 + ks * 32 + lq * 8;
            s8v ah  = *(const s8v*)&mhi[moff];
            s8v al_ = *(const s8v*)&mlo[moff];
#pragma unroll
            for (int fn = 0; fn < 4; ++fn) {
                acc[fo][fn] = __builtin_amdgcn_mfma_f32_16x16x32_bf16(
                    ah, bh[fn], acc[fo][fn], 0, 0, 0);
                acc[fo][fn] = __builtin_amdgcn_mfma_f32_16x16x32_bf16(
                    ah, bl[fn], acc[fo][fn], 0, 0, 0);
                acc[fo][fn] = __builtin_amdgcn_mfma_f32_16x16x32_bf16(
                    al_, bh[fn], acc[fo][fn], 0, 0, 0);
            }
        }
    }

#pragma unroll
    for (int fo = 0; fo < 4; ++fo) {
        const int orow = obase + fo * 16 + lq * 4;
#pragma unroll
        for (int fn = 0; fn < 4; ++fn) {
            const int nc = n0 + fn * 16 + lm;
            float* dst = out + ((size_t)b * 512 + orow) * NSP + nc;
#pragma unroll
            for (int r = 0; r < 4; ++r)
                dst[(size_t)r * NSP] = acc[fo][fn][r] + bo[orow + r];
        }
    }
}

// ---------------------------------------------------------------------------
extern "C" void kernel_launch(void* const* d_in, const int* in_sizes, int n_in,
                              void* d_out, int out_size, void* d_ws, size_t ws_size,
                              hipStream_t stream)
{
    const float* x  = (const float*)d_in[0];
    const float* Wq = (const float*)d_in[1];
    const float* bq = (const float*)d_in[2];
    const float* Wk = (const float*)d_in[3];
    const float* bk = (const float*)d_in[4];
    const float* Wv = (const float*)d_in[5];
    const float* bv = (const float*)d_in[6];
    const float* Wo = (const float*)d_in[7];
    const float* bo = (const float*)d_in[8];
    float* out = (float*)d_out;

    float* ws   = (float*)d_ws;
    float* v    = ws;                                    // [B,64,N]     16.8 MB
    float* part = v    + (size_t)B_SZ * 64 * NSP;        // [B,32,64,64]  8.4 MB
    unsigned short* mhi = (unsigned short*)(part + (size_t)B_SZ * 32 * 64 * 64);
    unsigned short* mlo = mhi + (size_t)B_SZ * 512 * 64; // 1 MiB each

    k_qkv_en<<<dim3(32, B_SZ), 512, 0, stream>>>(x, Wq, Wk, Wv, bq, bk, bv, v, part);
    k_sm_wo <<<dim3(8, B_SZ),  256, 0, stream>>>(part, Wo, mhi, mlo);
    k_out2  <<<dim3(64, B_SZ), 512, 0, stream>>>(v, mhi, mlo, bo, out);
}